// Round 8
// baseline (154.799 us; speedup 1.0000x reference)
//
#include <hip/hip_runtime.h>
#include <stdint.h>

typedef unsigned int u32;
typedef unsigned long long u64;

#define HW      3136     // 56*56
#define PADW    58
#define PADHW   3364     // 58*58

// d_ws layout
#define WB_OFF   0        // 4608 u32  (18432 B)  packed weights
#define BF_OFF   18432    // 9*128 f32 (4608 B)   per-(class,o) base, alpha-folded
#define N2A_OFF  23040    // 128 f32   (512 B)    -2*alpha
#define AB_OFF   23552    // 32*3364 uint4        padded activation bits

// prep grid split
#define NB_W     128      // weight-synthesis blocks (one per o)
#define NB_A     392      // apack interior: 32 b * 4 g * 784 quads / 256
#define NB_R     29       // ring-zero: 32 b * 228 ring px -> 7296 uint4 / 256

// ---------------------------------------------------------------------------
// Prep kernel, 3 block classes.
// [0,128):   weight synthesis + sign-pack + correction tables.
//            sign(w) = sign(m + rv.z) (rsqrt normalizer is positive).
// [128,520): activation sign-pack, float4-vectorized: thread = (b,g,quad),
//            32 coalesced float4 reads, 4 bit-words assembled in regs.
// [520,549): zero the 58x58 ring (228 px/image) so border taps read 0.
__global__ __launch_bounds__(256) void k_prep(
    const float* __restrict__ x, const float* __restrict__ Alpha,
    const float* __restrict__ M, const float* __restrict__ Z,
    const float* __restrict__ rv, char* __restrict__ ws)
{
  int t = threadIdx.x;
  if (blockIdx.x < NB_W) {
    // ---- weight synthesis for o = blockIdx.x ----
    u32*   wb  = (u32*)(ws + WB_OFF);
    float* Bf  = (float*)(ws + BF_OFF);
    float* n2a = (float*)(ws + N2A_OFF);
    __shared__ float sw[1152];
    __shared__ u32 sbits[36];
    __shared__ int spc[9];
    int o = blockIdx.x;
    float r0 = rv[0], r1 = rv[1], r2 = rv[2], r3 = rv[3], r4 = rv[4];
    const float4* M4 = (const float4*)M;
    const float4* Z4 = (const float4*)Z;
    float4* sw4 = (float4*)sw;

    for (int j = t; j < 288; j += 256) {
      float4 a = M4[o * 288 + j];
      float4 z;
      z = Z4[0 * 36864 + o * 288 + j];
      a.x = fmaf(r0, z.x, a.x); a.y = fmaf(r0, z.y, a.y);
      a.z = fmaf(r0, z.z, a.z); a.w = fmaf(r0, z.w, a.w);
      z = Z4[1 * 36864 + o * 288 + j];
      a.x = fmaf(r1, z.x, a.x); a.y = fmaf(r1, z.y, a.y);
      a.z = fmaf(r1, z.z, a.z); a.w = fmaf(r1, z.w, a.w);
      z = Z4[2 * 36864 + o * 288 + j];
      a.x = fmaf(r2, z.x, a.x); a.y = fmaf(r2, z.y, a.y);
      a.z = fmaf(r2, z.z, a.z); a.w = fmaf(r2, z.w, a.w);
      z = Z4[3 * 36864 + o * 288 + j];
      a.x = fmaf(r3, z.x, a.x); a.y = fmaf(r3, z.y, a.y);
      a.z = fmaf(r3, z.z, a.z); a.w = fmaf(r3, z.w, a.w);
      z = Z4[4 * 36864 + o * 288 + j];
      a.x = fmaf(r4, z.x, a.x); a.y = fmaf(r4, z.y, a.y);
      a.z = fmaf(r4, z.z, a.z); a.w = fmaf(r4, z.w, a.w);
      sw4[j] = a;
    }
    __syncthreads();

    if (t < 36) {                       // t = tap*4 + word
      int tap = t >> 2;
      int wd  = t & 3;
      u32 bits = 0;
#pragma unroll
      for (int c = 0; c < 32; ++c) {
        float v = sw[(wd * 32 + c) * 9 + tap];
        bits |= (v > 0.0f ? 1u : 0u) << c;
      }
      wb[(o * 9 + tap) * 4 + wd] = bits;
      sbits[t] = bits;
    }
    __syncthreads();
    if (t < 9)
      spc[t] = __popc(sbits[4 * t]) + __popc(sbits[4 * t + 1])
             + __popc(sbits[4 * t + 2]) + __popc(sbits[4 * t + 3]);
    __syncthreads();
    if (t < 9) {                        // t = edge class ht*3+wt
      int ht = t / 3, wt = t - ht * 3;
      int corr = 0;
#pragma unroll
      for (int tap = 0; tap < 9; ++tap) {
        int dh = tap / 3, dw = tap - dh * 3;
        int inv = ((ht == 0) & (dh == 0)) | ((ht == 2) & (dh == 2)) |
                  ((wt == 0) & (dw == 0)) | ((wt == 2) & (dw == 2));
        if (inv) corr += 128 - 2 * spc[tap];
      }
      Bf[t * 128 + o] = (float)(1152 - corr) * Alpha[o];
    }
    if (t == 0) n2a[o] = -2.0f * Alpha[o];
  } else if (blockIdx.x < NB_W + NB_A) {
    // ---- activation sign-pack, vectorized ----
    u32* abw = (u32*)(ws + AB_OFF);
    int idx = (blockIdx.x - NB_W) * 256 + t;  // (b*4+g)*784 + q
    int bg  = idx / 784;
    int q   = idx - bg * 784;                 // pixel quad 0..783
    int b   = bg >> 2;
    int g   = bg & 3;
    int h   = q / 14;                         // 4 | 56 -> no row wrap in quad
    int w0  = (q - h * 14) * 4;

    const float4* X4 = (const float4*)x
        + ((size_t)b * 128 + g * 32) * (HW / 4) + q;
    u32 m0 = 0, m1 = 0, m2 = 0, m3 = 0;
#pragma unroll
    for (int c = 0; c < 32; ++c) {
      float4 f = X4[(size_t)c * (HW / 4)];
      m0 |= (f.x > 0.0f ? 1u : 0u) << c;
      m1 |= (f.y > 0.0f ? 1u : 0u) << c;
      m2 |= (f.z > 0.0f ? 1u : 0u) << c;
      m3 |= (f.w > 0.0f ? 1u : 0u) << c;
    }
    size_t base = ((size_t)b * PADHW + (h + 1) * PADW + (w0 + 1)) * 4 + g;
    abw[base]      = m0;
    abw[base + 4]  = m1;
    abw[base + 8]  = m2;
    abw[base + 12] = m3;
  } else {
    // ---- ring zero ----
    uint4* ab4 = (uint4*)(ws + AB_OFF);
    int e = (blockIdx.x - NB_W - NB_A) * 256 + t;
    if (e >= 32 * 228) return;
    int b  = e / 228;
    int r  = e - b * 228;
    int pp;
    if      (r < 58)  pp = r;                       // top row
    else if (r < 116) pp = 57 * PADW + (r - 58);    // bottom row
    else {                                          // sides
      int s = r - 116;
      pp = (1 + (s >> 1)) * PADW + ((s & 1) ? 57 : 0);
    }
    ab4[(size_t)b * PADHW + pp] = make_uint4(0, 0, 0, 0);
  }
}

// ---------------------------------------------------------------------------
// Conv: uniform for ALL pixels (zero ring + correction table replaces edge
// masking). 256-thread blocks (4 co-resident waves hide each other's LDS/
// global latency — the combination R5/R6/R7 never tried together with LDS
// weights). Thread = 4 w-consecutive pixels (aligned quad) x 8 o's.
// Grid (98, 16): 98*256 = 25088 = 32*784 quads; blockIdx.y = og.
// s = unmasked 9-tap popc; out = fmaf(s, -2a[o], Bf[class][o]).
__global__ __launch_bounds__(256, 4) void k_conv(
    const char* __restrict__ ws, float* __restrict__ out)
{
  const uint4*  ab  = (const uint4*)(ws + AB_OFF);
  const uint4*  wbg = (const uint4*)(ws + WB_OFF);
  const float*  BfG = (const float*)(ws + BF_OFF);
  const float*  n2a = (const float*)(ws + N2A_OFF);

  __shared__ uint4 swb[72];        // 8 o x 9 taps
  __shared__ float sBf[9][8];      // class x o
  __shared__ float sn2a[8];
  int tid = threadIdx.x;           // 0..255
  int og  = blockIdx.y;            // 0..15
  int o0  = og * 8;
  if (tid < 72) {
    swb[tid] = wbg[o0 * 9 + tid];
    (&sBf[0][0])[tid] = BfG[(tid >> 3) * 128 + o0 + (tid & 7)];
  }
  if (tid < 8) sn2a[tid] = n2a[o0 + tid];
  __syncthreads();

  int q  = blockIdx.x * 256 + tid;      // 0..25087
  int b  = q / 784;
  int r  = q - b * 784;
  int h  = r / 14;
  int w4 = r - h * 14;
  int w0 = w4 * 4;

  // taps: padded rows h..h+2, cols w0..w0+5
  const uint4* ap = ab + ((size_t)b * PADW + h) * PADW + w0;
  u32 A[3][6][4];
#pragma unroll
  for (int rr = 0; rr < 3; ++rr)
#pragma unroll
    for (int cc = 0; cc < 6; ++cc) {
      uint4 v = ap[(size_t)rr * PADW + cc];
      A[rr][cc][0] = v.x; A[rr][cc][1] = v.y;
      A[rr][cc][2] = v.z; A[rr][cc][3] = v.w;
    }

  int ht  = (h == 0) ? 0 : (h == 55 ? 6 : 3);
  int cl0 = ht + ((w0 == 0) ? 0 : 1);
  int cl1 = ht + 1;
  int cl3 = ht + ((w0 == 52) ? 2 : 1);

  float* outp = out + ((size_t)b * 128 + o0) * HW + h * 56 + w0;

#pragma unroll
  for (int oi = 0; oi < 8; ++oi) {
    int s0 = 0, s1 = 0, s2 = 0, s3 = 0;
#pragma unroll
    for (int dh = 0; dh < 3; ++dh)
#pragma unroll
      for (int dw = 0; dw < 3; ++dw) {
        uint4 wv = swb[oi * 9 + dh * 3 + dw];
#pragma unroll
        for (int k = 0; k < 4; ++k) {
          u32 wk = (&wv.x)[k];
          s0 += __popc(A[dh][dw + 0][k] ^ wk);
          s1 += __popc(A[dh][dw + 1][k] ^ wk);
          s2 += __popc(A[dh][dw + 2][k] ^ wk);
          s3 += __popc(A[dh][dw + 3][k] ^ wk);
        }
      }
    float na = sn2a[oi];
    float4 ov;
    ov.x = fmaf((float)s0, na, sBf[cl0][oi]);
    ov.y = fmaf((float)s1, na, sBf[cl1][oi]);
    ov.z = fmaf((float)s2, na, sBf[cl1][oi]);
    ov.w = fmaf((float)s3, na, sBf[cl3][oi]);
    *(float4*)(outp + (size_t)oi * HW) = ov;
  }
}

// ---------------------------------------------------------------------------
extern "C" void kernel_launch(void* const* d_in, const int* in_sizes, int n_in,
                              void* d_out, int out_size, void* d_ws, size_t ws_size,
                              hipStream_t stream)
{
  const float* x     = (const float*)d_in[0];
  const float* Alpha = (const float*)d_in[1];
  const float* M     = (const float*)d_in[2];
  const float* Z     = (const float*)d_in[3];
  const float* rv    = (const float*)d_in[4];
  float* out         = (float*)d_out;
  char*  ws          = (char*)d_ws;

  k_prep<<<NB_W + NB_A + NB_R, 256, 0, stream>>>(x, Alpha, M, Z, rv, ws);
  k_conv<<<dim3(98, 16), 256, 0, stream>>>(ws, out);
}

// Round 9
// 135.888 us; speedup vs baseline: 1.1392x; 1.1392x over previous
//
#include <hip/hip_runtime.h>
#include <stdint.h>

typedef unsigned int u32;
typedef unsigned long long u64;

#define HW      3136     // 56*56
#define PADW    58
#define PADHW   3364     // 58*58

// d_ws layout
#define WB_OFF   0        // 4608 u32  (18432 B)  packed weights
#define BF_OFF   18432    // 9*128 f32 (4608 B)   per-(class,o) base, alpha-folded
#define N2A_OFF  23040    // 128 f32   (512 B)    -2*alpha
#define AB_OFF   23552    // 32*3364 uint4        padded activation bits

// prep grid split
#define NB_W     128      // weight-synthesis blocks (one per o)
#define NB_A     392      // apack interior: 32 b * 4 g * 784 quads / 256
#define NB_R     29       // ring-zero: 32 b * 228 ring px -> 7296 uint4 / 256

// ---------------------------------------------------------------------------
// Prep kernel, 3 block classes.
// [0,128):   weight synthesis + sign-pack + correction tables.
//            sign(w) = sign(m + rv.z) (rsqrt normalizer is positive).
// [128,520): activation sign-pack, float4-vectorized: thread = (b,g,quad),
//            32 coalesced float4 reads, 4 bit-words assembled in regs.
// [520,549): zero the 58x58 ring (228 px/image) so border taps read 0.
__global__ __launch_bounds__(256) void k_prep(
    const float* __restrict__ x, const float* __restrict__ Alpha,
    const float* __restrict__ M, const float* __restrict__ Z,
    const float* __restrict__ rv, char* __restrict__ ws)
{
  int t = threadIdx.x;
  if (blockIdx.x < NB_W) {
    // ---- weight synthesis for o = blockIdx.x ----
    u32*   wb  = (u32*)(ws + WB_OFF);
    float* Bf  = (float*)(ws + BF_OFF);
    float* n2a = (float*)(ws + N2A_OFF);
    __shared__ float sw[1152];
    __shared__ u32 sbits[36];
    __shared__ int spc[9];
    int o = blockIdx.x;
    float r0 = rv[0], r1 = rv[1], r2 = rv[2], r3 = rv[3], r4 = rv[4];
    const float4* M4 = (const float4*)M;
    const float4* Z4 = (const float4*)Z;
    float4* sw4 = (float4*)sw;

    for (int j = t; j < 288; j += 256) {
      float4 a = M4[o * 288 + j];
      float4 z;
      z = Z4[0 * 36864 + o * 288 + j];
      a.x = fmaf(r0, z.x, a.x); a.y = fmaf(r0, z.y, a.y);
      a.z = fmaf(r0, z.z, a.z); a.w = fmaf(r0, z.w, a.w);
      z = Z4[1 * 36864 + o * 288 + j];
      a.x = fmaf(r1, z.x, a.x); a.y = fmaf(r1, z.y, a.y);
      a.z = fmaf(r1, z.z, a.z); a.w = fmaf(r1, z.w, a.w);
      z = Z4[2 * 36864 + o * 288 + j];
      a.x = fmaf(r2, z.x, a.x); a.y = fmaf(r2, z.y, a.y);
      a.z = fmaf(r2, z.z, a.z); a.w = fmaf(r2, z.w, a.w);
      z = Z4[3 * 36864 + o * 288 + j];
      a.x = fmaf(r3, z.x, a.x); a.y = fmaf(r3, z.y, a.y);
      a.z = fmaf(r3, z.z, a.z); a.w = fmaf(r3, z.w, a.w);
      z = Z4[4 * 36864 + o * 288 + j];
      a.x = fmaf(r4, z.x, a.x); a.y = fmaf(r4, z.y, a.y);
      a.z = fmaf(r4, z.z, a.z); a.w = fmaf(r4, z.w, a.w);
      sw4[j] = a;
    }
    __syncthreads();

    if (t < 36) {                       // t = tap*4 + word
      int tap = t >> 2;
      int wd  = t & 3;
      u32 bits = 0;
#pragma unroll
      for (int c = 0; c < 32; ++c) {
        float v = sw[(wd * 32 + c) * 9 + tap];
        bits |= (v > 0.0f ? 1u : 0u) << c;
      }
      wb[(o * 9 + tap) * 4 + wd] = bits;
      sbits[t] = bits;
    }
    __syncthreads();
    if (t < 9)
      spc[t] = __popc(sbits[4 * t]) + __popc(sbits[4 * t + 1])
             + __popc(sbits[4 * t + 2]) + __popc(sbits[4 * t + 3]);
    __syncthreads();
    if (t < 9) {                        // t = edge class ht*3+wt
      int ht = t / 3, wt = t - ht * 3;
      int corr = 0;
#pragma unroll
      for (int tap = 0; tap < 9; ++tap) {
        int dh = tap / 3, dw = tap - dh * 3;
        int inv = ((ht == 0) & (dh == 0)) | ((ht == 2) & (dh == 2)) |
                  ((wt == 0) & (dw == 0)) | ((wt == 2) & (dw == 2));
        if (inv) corr += 128 - 2 * spc[tap];
      }
      Bf[t * 128 + o] = (float)(1152 - corr) * Alpha[o];
    }
    if (t == 0) n2a[o] = -2.0f * Alpha[o];
  } else if (blockIdx.x < NB_W + NB_A) {
    // ---- activation sign-pack, vectorized ----
    u32* abw = (u32*)(ws + AB_OFF);
    int idx = (blockIdx.x - NB_W) * 256 + t;  // (b*4+g)*784 + q
    int bg  = idx / 784;
    int q   = idx - bg * 784;                 // pixel quad 0..783
    int b   = bg >> 2;
    int g   = bg & 3;
    int h   = q / 14;                         // 4 | 56 -> no row wrap in quad
    int w0  = (q - h * 14) * 4;

    const float4* X4 = (const float4*)x
        + ((size_t)b * 128 + g * 32) * (HW / 4) + q;
    u32 m0 = 0, m1 = 0, m2 = 0, m3 = 0;
#pragma unroll
    for (int c = 0; c < 32; ++c) {
      float4 f = X4[(size_t)c * (HW / 4)];
      m0 |= (f.x > 0.0f ? 1u : 0u) << c;
      m1 |= (f.y > 0.0f ? 1u : 0u) << c;
      m2 |= (f.z > 0.0f ? 1u : 0u) << c;
      m3 |= (f.w > 0.0f ? 1u : 0u) << c;
    }
    size_t base = ((size_t)b * PADHW + (h + 1) * PADW + (w0 + 1)) * 4 + g;
    abw[base]      = m0;
    abw[base + 4]  = m1;
    abw[base + 8]  = m2;
    abw[base + 12] = m3;
  } else {
    // ---- ring zero ----
    uint4* ab4 = (uint4*)(ws + AB_OFF);
    int e = (blockIdx.x - NB_W - NB_A) * 256 + t;
    if (e >= 32 * 228) return;
    int b  = e / 228;
    int r  = e - b * 228;
    int pp;
    if      (r < 58)  pp = r;                       // top row
    else if (r < 116) pp = 57 * PADW + (r - 58);    // bottom row
    else {                                          // sides
      int s = r - 116;
      pp = (1 + (s >> 1)) * PADW + ((s & 1) ? 57 : 0);
    }
    ab4[(size_t)b * PADHW + pp] = make_uint4(0, 0, 0, 0);
  }
}

// ---------------------------------------------------------------------------
// Conv: uniform for ALL pixels (zero ring + correction table replaces edge
// masking). 256-thread blocks (4 co-resident waves hide LDS/VMEM latency),
// __launch_bounds__(256, 1): min-1-wave cap (512 VGPR) so the allocator
// holds A[3][6][4] (~100 regs total) WITHOUT the scratch spill that R8's
// min-4 bound caused (VGPR=64 -> +113 MB HBM spill traffic).
// Thread = 4 w-consecutive pixels (aligned quad) x 8 o's.
// Grid (98, 16): 98*256 = 25088 = 32*784 quads; blockIdx.y = og.
// s = unmasked 9-tap popc; out = fmaf(s, -2a[o], Bf[class][o]).
__global__ __launch_bounds__(256, 1) void k_conv(
    const char* __restrict__ ws, float* __restrict__ out)
{
  const uint4*  ab  = (const uint4*)(ws + AB_OFF);
  const uint4*  wbg = (const uint4*)(ws + WB_OFF);
  const float*  BfG = (const float*)(ws + BF_OFF);
  const float*  n2a = (const float*)(ws + N2A_OFF);

  __shared__ uint4 swb[72];        // 8 o x 9 taps
  __shared__ float sBf[9][8];      // class x o
  __shared__ float sn2a[8];
  int tid = threadIdx.x;           // 0..255
  int og  = blockIdx.y;            // 0..15
  int o0  = og * 8;
  if (tid < 72) {
    swb[tid] = wbg[o0 * 9 + tid];
    (&sBf[0][0])[tid] = BfG[(tid >> 3) * 128 + o0 + (tid & 7)];
  }
  if (tid < 8) sn2a[tid] = n2a[o0 + tid];
  __syncthreads();

  int q  = blockIdx.x * 256 + tid;      // 0..25087
  int b  = q / 784;
  int r  = q - b * 784;
  int h  = r / 14;
  int w4 = r - h * 14;
  int w0 = w4 * 4;

  // taps: padded rows h..h+2, cols w0..w0+5
  const uint4* ap = ab + ((size_t)b * PADW + h) * PADW + w0;
  u32 A[3][6][4];
#pragma unroll
  for (int rr = 0; rr < 3; ++rr)
#pragma unroll
    for (int cc = 0; cc < 6; ++cc) {
      uint4 v = ap[(size_t)rr * PADW + cc];
      A[rr][cc][0] = v.x; A[rr][cc][1] = v.y;
      A[rr][cc][2] = v.z; A[rr][cc][3] = v.w;
    }

  int ht  = (h == 0) ? 0 : (h == 55 ? 6 : 3);
  int cl0 = ht + ((w0 == 0) ? 0 : 1);
  int cl1 = ht + 1;
  int cl3 = ht + ((w0 == 52) ? 2 : 1);

  float* outp = out + ((size_t)b * 128 + o0) * HW + h * 56 + w0;

#pragma unroll
  for (int oi = 0; oi < 8; ++oi) {
    int s0 = 0, s1 = 0, s2 = 0, s3 = 0;
#pragma unroll
    for (int dh = 0; dh < 3; ++dh)
#pragma unroll
      for (int dw = 0; dw < 3; ++dw) {
        uint4 wv = swb[oi * 9 + dh * 3 + dw];
#pragma unroll
        for (int k = 0; k < 4; ++k) {
          u32 wk = (&wv.x)[k];
          s0 += __popc(A[dh][dw + 0][k] ^ wk);
          s1 += __popc(A[dh][dw + 1][k] ^ wk);
          s2 += __popc(A[dh][dw + 2][k] ^ wk);
          s3 += __popc(A[dh][dw + 3][k] ^ wk);
        }
      }
    float na = sn2a[oi];
    float4 ov;
    ov.x = fmaf((float)s0, na, sBf[cl0][oi]);
    ov.y = fmaf((float)s1, na, sBf[cl1][oi]);
    ov.z = fmaf((float)s2, na, sBf[cl1][oi]);
    ov.w = fmaf((float)s3, na, sBf[cl3][oi]);
    *(float4*)(outp + (size_t)oi * HW) = ov;
  }
}

// ---------------------------------------------------------------------------
extern "C" void kernel_launch(void* const* d_in, const int* in_sizes, int n_in,
                              void* d_out, int out_size, void* d_ws, size_t ws_size,
                              hipStream_t stream)
{
  const float* x     = (const float*)d_in[0];
  const float* Alpha = (const float*)d_in[1];
  const float* M     = (const float*)d_in[2];
  const float* Z     = (const float*)d_in[3];
  const float* rv    = (const float*)d_in[4];
  float* out         = (float*)d_out;
  char*  ws          = (char*)d_ws;

  k_prep<<<NB_W + NB_A + NB_R, 256, 0, stream>>>(x, Alpha, M, Z, rv, ws);
  k_conv<<<dim3(98, 16), 256, 0, stream>>>(ws, out);
}